// Round 1
// baseline (337.700 us; speedup 1.0000x reference)
//
#include <hip/hip_runtime.h>
#include <math.h>

#define N_NODES 40000
#define N_EDGES 640000
#define D_FEAT 128

// ---------------- zero the workspace header ----------------
__global__ void zero_kernel(int* __restrict__ p, int n) {
    int i = blockIdx.x * blockDim.x + threadIdx.x;
    if (i < n) p[i] = 0;
}

// ---------------- 1/||x_i|| : one wave (64 lanes) per node ----------------
__global__ void rinv_kernel(const float* __restrict__ x, float* __restrict__ rinv, int n) {
    int gid  = blockIdx.x * blockDim.x + threadIdx.x;
    int node = gid >> 6;
    int lane = gid & 63;
    if (node >= n) return;
    const float2* xp = (const float2*)(x + (size_t)node * D_FEAT);
    float2 v = xp[lane];                 // 64 lanes x 8B = 512B coalesced
    float s = v.x * v.x + v.y * v.y;
    #pragma unroll
    for (int m = 32; m; m >>= 1) s += __shfl_xor(s, m);
    if (lane == 0) rinv[node] = 1.0f / sqrtf(s);
}

// ---------------- histogram of destination (row) degrees ----------------
__global__ void hist_kernel(const int* __restrict__ row, int* __restrict__ count, int n) {
    int i = blockIdx.x * blockDim.x + threadIdx.x;
    if (i < n) atomicAdd(&count[row[i]], 1);
}

// ---------------- exclusive prefix sum, single block of 1024 ----------------
__global__ void scan_kernel(const int* __restrict__ count, int* __restrict__ offs, int n) {
    __shared__ int buf[1024];
    int tid = threadIdx.x;
    int base = 0;                         // same value in every thread
    for (int start = 0; start < n; start += 1024) {
        int i = start + tid;
        int v = (i < n) ? count[i] : 0;
        buf[tid] = v;
        __syncthreads();
        for (int off = 1; off < 1024; off <<= 1) {
            int t = (tid >= off) ? buf[tid - off] : 0;
            __syncthreads();
            buf[tid] += t;
            __syncthreads();
        }
        if (i < n) offs[i] = base + buf[tid] - v;   // exclusive
        int tot = buf[1023];
        __syncthreads();
        base += tot;
    }
    if (tid == 0) offs[n] = base;
}

// ---------------- per-edge: cosine sim, exp, CSR scatter, denom ----------------
__global__ void edge_kernel(const float* __restrict__ x,
                            const int* __restrict__ row, const int* __restrict__ col,
                            const float* __restrict__ rinv, const float* __restrict__ beta,
                            const int* __restrict__ offs, int* __restrict__ cursor,
                            float* __restrict__ denom,
                            int* __restrict__ csr_col, float* __restrict__ csr_w, int nE) {
    int gid  = blockIdx.x * blockDim.x + threadIdx.x;
    int e    = gid >> 6;          // one wave per edge
    int lane = gid & 63;
    if (e >= nE) return;
    int r = row[e], c = col[e];
    const float2* xr = (const float2*)(x + (size_t)r * D_FEAT);
    const float2* xc = (const float2*)(x + (size_t)c * D_FEAT);
    float2 a = xr[lane];
    float2 b = xc[lane];
    float s = a.x * b.x + a.y * b.y;
    #pragma unroll
    for (int m = 32; m; m >>= 1) s += __shfl_xor(s, m);
    if (lane == 0) {
        float w = __expf(s * rinv[r] * rinv[c] * beta[0]);
        int pos = offs[r] + atomicAdd(&cursor[r], 1);
        csr_col[pos] = c;
        csr_w[pos]   = w;
        atomicAdd(&denom[r], w);
    }
}

// ---------------- SpMM: one 128-thread block per destination node ----------------
__global__ void spmm_kernel(const float* __restrict__ x, const float* __restrict__ beta,
                            const int* __restrict__ offs, const float* __restrict__ denom,
                            const int* __restrict__ csr_col, const float* __restrict__ csr_w,
                            float* __restrict__ out) {
    int n = blockIdx.x;
    int d = threadIdx.x;
    float selfw = __expf(beta[0]);           // self-loop: cos = 1 -> alpha = beta
    float acc = selfw * x[(size_t)n * D_FEAT + d];
    int s = offs[n], e = offs[n + 1];
    for (int p = s; p < e; p++) {
        int   c = csr_col[p];                // broadcast load (same addr all lanes)
        float w = csr_w[p];
        acc += w * x[(size_t)c * D_FEAT + d];  // 512B coalesced gather
    }
    out[(size_t)n * D_FEAT + d] = acc / (denom[n] + selfw);
}

extern "C" void kernel_launch(void* const* d_in, const int* in_sizes, int n_in,
                              void* d_out, int out_size, void* d_ws, size_t ws_size,
                              hipStream_t stream) {
    const float* x    = (const float*)d_in[0];
    const float* beta = (const float*)d_in[1];
    const int*   ei   = (const int*)d_in[2];
    const int*   row  = ei;              // edge_index[0] = destination
    const int*   col  = ei + N_EDGES;    // edge_index[1] = source
    float* out = (float*)d_out;

    // workspace layout (all 4B-aligned)
    int*   count   = (int*)d_ws;                    // N+1
    int*   cursor  = count  + (N_NODES + 1);        // N
    int*   offs    = cursor + N_NODES;              // N+1
    float* rinv    = (float*)(offs + (N_NODES + 1)); // N
    float* denom   = rinv   + N_NODES;              // N
    int*   csr_col = (int*)(denom + N_NODES);       // E
    float* csr_w   = (float*)(csr_col + N_EDGES);   // E

    int hdr = 2 * (N_NODES + 1) + 3 * N_NODES;      // zero count/cursor/offs/rinv/denom
    zero_kernel<<<(hdr + 255) / 256, 256, 0, stream>>>((int*)d_ws, hdr);

    rinv_kernel<<<(N_NODES * 64 + 255) / 256, 256, 0, stream>>>(x, rinv, N_NODES);

    hist_kernel<<<(N_EDGES + 255) / 256, 256, 0, stream>>>(row, count, N_EDGES);

    scan_kernel<<<1, 1024, 0, stream>>>(count, offs, N_NODES);

    edge_kernel<<<(N_EDGES * 64 + 255) / 256, 256, 0, stream>>>(
        x, row, col, rinv, beta, offs, cursor, denom, csr_col, csr_w, N_EDGES);

    spmm_kernel<<<N_NODES, D_FEAT, 0, stream>>>(x, beta, offs, denom, csr_col, csr_w, out);
}

// Round 3
// 147.128 us; speedup vs baseline: 2.2953x; 2.2953x over previous
//
#include <hip/hip_runtime.h>
#include <math.h>

#define N_NODES 40000
#define N_EDGES 640000
#define D_FEAT 128
#define SCAN_B 1024
#define NB ((N_NODES + SCAN_B - 1) / SCAN_B)   // 40 blocks

// ---------------- zero count/cursor ----------------
__global__ void zero_kernel(int* __restrict__ p, int n) {
    int i = blockIdx.x * blockDim.x + threadIdx.x;
    if (i < n) p[i] = 0;
}

// ---------------- 1/||x_i|| : one wave per node ----------------
__global__ void rinv_kernel(const float* __restrict__ x, float* __restrict__ rinv, int n) {
    int gid  = blockIdx.x * blockDim.x + threadIdx.x;
    int node = gid >> 6;
    int lane = gid & 63;
    if (node >= n) return;
    const float2* xp = (const float2*)(x + (size_t)node * D_FEAT);
    float2 v = xp[lane];
    float s = v.x * v.x + v.y * v.y;
    #pragma unroll
    for (int m = 32; m; m >>= 1) s += __shfl_xor(s, m);
    if (lane == 0) rinv[node] = 1.0f / sqrtf(s);
}

// ---------------- destination-degree histogram ----------------
__global__ void hist_kernel(const int* __restrict__ row, int* __restrict__ count, int n) {
    int i = blockIdx.x * blockDim.x + threadIdx.x;
    if (i < n) atomicAdd(&count[row[i]], 1);
}

// ---------------- hierarchical scan: stage 1 (per-1024 block, shuffle-based) ----------------
__global__ void scan1_kernel(const int* __restrict__ count, int* __restrict__ offs,
                             int* __restrict__ blocksum, int n) {
    __shared__ int wsum[16];
    int tid = threadIdx.x;
    int gid = blockIdx.x * SCAN_B + tid;
    int v = (gid < n) ? count[gid] : 0;
    int s = v;
    #pragma unroll
    for (int off = 1; off < 64; off <<= 1) {        // inclusive wave scan
        int t = __shfl_up(s, off);
        if ((tid & 63) >= off) s += t;
    }
    if ((tid & 63) == 63) wsum[tid >> 6] = s;
    __syncthreads();
    if (tid < 16) {                                  // scan the 16 wave totals
        int t = wsum[tid];
        #pragma unroll
        for (int off = 1; off < 16; off <<= 1) {
            int u = __shfl_up(t, off);
            if (tid >= off) t += u;
        }
        wsum[tid] = t;                               // inclusive
    }
    __syncthreads();
    int base = (tid >= 64) ? wsum[(tid >> 6) - 1] : 0;
    int inc = base + s;                              // inclusive within block
    if (gid < n) offs[gid] = inc - v;                // exclusive within block
    if (tid == SCAN_B - 1) blocksum[blockIdx.x] = inc;
}

// ---------------- stage 2: exclusive scan of the 40 block totals (one wave) ----------------
__global__ void scan2_kernel(int* __restrict__ blocksum, int nb) {
    int tid = threadIdx.x;                           // 64 threads
    int v = (tid < nb) ? blocksum[tid] : 0;
    int s = v;
    #pragma unroll
    for (int off = 1; off < 64; off <<= 1) {
        int t = __shfl_up(s, off);
        if (tid >= off) s += t;
    }
    if (tid < nb) blocksum[tid] = s - v;             // exclusive base
}

// ---------------- stage 3: add block bases, finalize offs ----------------
__global__ void scan3_kernel(int* __restrict__ offs, const int* __restrict__ blocksum, int n) {
    int gid = blockIdx.x * blockDim.x + threadIdx.x;
    if (gid < n) offs[gid] += blocksum[gid >> 10];
    if (gid == 0) offs[n] = N_EDGES;
}

// ---------------- scatter source indices into CSR slots ----------------
__global__ void scatter_kernel(const int* __restrict__ row, const int* __restrict__ col,
                               const int* __restrict__ offs, int* __restrict__ cursor,
                               int* __restrict__ csr_col, int n) {
    int i = blockIdx.x * blockDim.x + threadIdx.x;
    if (i < n) {
        int r = row[i];
        int pos = offs[r] + atomicAdd(&cursor[r], 1);
        csr_col[pos] = col[i];
    }
}

// ---------------- fused: dot + exp + weighted aggregate, one wave per node ----------------
// Wave split into two 32-lane halves; each half handles one neighbor per iteration
// (float4 per lane covers the 128 features). x[c] read exactly once per edge.
__global__ void fused_kernel(const float* __restrict__ x,
                             const float* __restrict__ beta,
                             const float* __restrict__ rinv,
                             const int* __restrict__ offs,
                             const int* __restrict__ csr_col,
                             float* __restrict__ out) {
    int wid  = threadIdx.x >> 6;
    int lane = threadIdx.x & 63;
    int node = blockIdx.x * (blockDim.x >> 6) + wid;
    if (node >= N_NODES) return;
    int half = lane >> 5;                            // 0 or 1
    int hl   = lane & 31;
    const float4* xn = (const float4*)(x + (size_t)node * D_FEAT);
    float4 a = xn[hl];
    float b0 = beta[0];
    float rnb = rinv[node] * b0;
    float selfw = __expf(b0);                        // self-loop: cos = 1 -> alpha = beta
    float4 acc;
    float den;
    if (half == 0) {
        acc = make_float4(selfw * a.x, selfw * a.y, selfw * a.z, selfw * a.w);
        den = selfw;
    } else {
        acc = make_float4(0.f, 0.f, 0.f, 0.f);
        den = 0.f;
    }
    int s = offs[node], e = offs[node + 1];
    for (int p = s; p < e; p += 2) {
        int idx = p + half;
        bool valid = idx < e;
        int c = csr_col[valid ? idx : p];            // tail: half1 re-reads half0's row (L2 hit)
        const float4* xc = (const float4*)(x + (size_t)c * D_FEAT);
        float4 bv = xc[hl];
        float dot = a.x * bv.x + a.y * bv.y + a.z * bv.z + a.w * bv.w;
        #pragma unroll
        for (int m = 1; m < 32; m <<= 1) dot += __shfl_xor(dot, m);   // within-half reduce
        float w = valid ? __expf(dot * rnb * rinv[c]) : 0.f;
        acc.x += w * bv.x; acc.y += w * bv.y; acc.z += w * bv.z; acc.w += w * bv.w;
        den += w;
    }
    // combine the two halves (same feature mapping in both)
    acc.x += __shfl_xor(acc.x, 32);
    acc.y += __shfl_xor(acc.y, 32);
    acc.z += __shfl_xor(acc.z, 32);
    acc.w += __shfl_xor(acc.w, 32);
    den   += __shfl_xor(den, 32);
    if (half == 0) {
        float inv = 1.0f / den;
        float4* op = (float4*)(out + (size_t)node * D_FEAT);
        op[hl] = make_float4(acc.x * inv, acc.y * inv, acc.z * inv, acc.w * inv);
    }
}

extern "C" void kernel_launch(void* const* d_in, const int* in_sizes, int n_in,
                              void* d_out, int out_size, void* d_ws, size_t ws_size,
                              hipStream_t stream) {
    const float* x    = (const float*)d_in[0];
    const float* beta = (const float*)d_in[1];
    const int*   ei   = (const int*)d_in[2];
    const int*   row  = ei;              // edge_index[0] = destination
    const int*   col  = ei + N_EDGES;    // edge_index[1] = source
    float* out = (float*)d_out;

    // workspace layout (ints/floats, 4B each)
    int*   count    = (int*)d_ws;                     // N
    int*   cursor   = count  + N_NODES;               // N
    int*   offs     = cursor + N_NODES;               // N+1
    int*   blocksum = offs   + (N_NODES + 1);         // NB
    float* rinv     = (float*)(blocksum + NB);        // N
    int*   csr_col  = (int*)(rinv + N_NODES);         // E

    zero_kernel<<<(2 * N_NODES + 255) / 256, 256, 0, stream>>>(count, 2 * N_NODES);

    rinv_kernel<<<(N_NODES * 64 + 255) / 256, 256, 0, stream>>>(x, rinv, N_NODES);

    hist_kernel<<<(N_EDGES + 255) / 256, 256, 0, stream>>>(row, count, N_EDGES);

    scan1_kernel<<<NB, SCAN_B, 0, stream>>>(count, offs, blocksum, N_NODES);
    scan2_kernel<<<1, 64, 0, stream>>>(blocksum, NB);
    scan3_kernel<<<(N_NODES + 255) / 256, 256, 0, stream>>>(offs, blocksum, N_NODES);

    scatter_kernel<<<(N_EDGES + 255) / 256, 256, 0, stream>>>(row, col, offs, cursor, csr_col, N_EDGES);

    fused_kernel<<<(N_NODES + 3) / 4, 256, 0, stream>>>(x, beta, rinv, offs, csr_col, out);
}

// Round 4
// 123.458 us; speedup vs baseline: 2.7353x; 1.1917x over previous
//
#include <hip/hip_runtime.h>
#include <math.h>

#define N_NODES 40000
#define N_EDGES 640000
#define D_FEAT 128
#define SCAN_B 1024
#define NB ((N_NODES + SCAN_B - 1) / SCAN_B)   // 40 blocks

// ---------------- zero count + cursor ----------------
__global__ void zero_kernel(int* __restrict__ p, int n) {
    int i = blockIdx.x * blockDim.x + threadIdx.x;
    if (i < n) p[i] = 0;
}

// ---------------- fused: destination-degree histogram + 1/||x_i|| ----------------
// 2.56M threads: thread i (i < E) histograms edge i; wave (i>>6) computes rinv of node (i>>6).
__global__ void hist_rinv_kernel(const int* __restrict__ row, int* __restrict__ count,
                                 const float* __restrict__ x, float* __restrict__ rinv) {
    int i = blockIdx.x * blockDim.x + threadIdx.x;
    if (i < N_EDGES) atomicAdd(&count[row[i]], 1);
    int node = i >> 6;
    int lane = i & 63;
    if (node < N_NODES) {
        const float2* xp = (const float2*)(x + (size_t)node * D_FEAT);
        float2 v = xp[lane];
        float s = v.x * v.x + v.y * v.y;
        #pragma unroll
        for (int m = 32; m; m >>= 1) s += __shfl_xor(s, m);
        if (lane == 0) rinv[node] = 1.0f / sqrtf(s);
    }
}

// ---------------- scan stage 1: per-1024-chunk exclusive scan (shuffle-based) ----------------
__global__ void scan1_kernel(const int* __restrict__ count, int* __restrict__ offs,
                             int* __restrict__ blocksum, int n) {
    __shared__ int wsum[16];
    int tid = threadIdx.x;
    int gid = blockIdx.x * SCAN_B + tid;
    int v = (gid < n) ? count[gid] : 0;
    int s = v;
    #pragma unroll
    for (int off = 1; off < 64; off <<= 1) {        // inclusive wave scan
        int t = __shfl_up(s, off);
        if ((tid & 63) >= off) s += t;
    }
    if ((tid & 63) == 63) wsum[tid >> 6] = s;
    __syncthreads();
    if (tid < 16) {                                  // scan the 16 wave totals
        int t = wsum[tid];
        #pragma unroll
        for (int off = 1; off < 16; off <<= 1) {
            int u = __shfl_up(t, off);
            if (tid >= off) t += u;
        }
        wsum[tid] = t;                               // inclusive
    }
    __syncthreads();
    int base = (tid >= 64) ? wsum[(tid >> 6) - 1] : 0;
    int inc = base + s;                              // inclusive within chunk
    if (gid < n) offs[gid] = inc - v;                // exclusive within chunk
    if (tid == SCAN_B - 1) blocksum[blockIdx.x] = inc;
}

// ---------------- scan stage 2: exclusive scan of the 40 chunk totals ----------------
__global__ void scan2_kernel(int* __restrict__ blocksum, int nb) {
    int tid = threadIdx.x;                           // 64 threads
    int v = (tid < nb) ? blocksum[tid] : 0;
    int s = v;
    #pragma unroll
    for (int off = 1; off < 64; off <<= 1) {
        int t = __shfl_up(s, off);
        if (tid >= off) s += t;
    }
    if (tid < nb) blocksum[tid] = s - v;             // exclusive chunk base
}

// ---------------- scatter source indices into CSR slots (chunk base folded in) ----------------
__global__ void scatter_kernel(const int* __restrict__ row, const int* __restrict__ col,
                               const int* __restrict__ offs, const int* __restrict__ bsum,
                               int* __restrict__ cursor, int* __restrict__ csr_col, int n) {
    int i = blockIdx.x * blockDim.x + threadIdx.x;
    if (i < n) {
        int r = row[i];
        int pos = offs[r] + bsum[r >> 10] + atomicAdd(&cursor[r], 1);
        csr_col[pos] = col[i];
    }
}

// ---------------- fused dot + exp + weighted aggregate ----------------
// One wave per node, four 16-lane groups -> 4 edges in flight; each lane holds
// 8 features (2 x float4). In-group reduce: 4 shuffle steps serve 4 edges.
__global__ void fused_kernel(const float* __restrict__ x,
                             const float* __restrict__ beta,
                             const float* __restrict__ rinv,
                             const int* __restrict__ offs,
                             const int* __restrict__ bsum,
                             const int* __restrict__ csr_col,
                             float* __restrict__ out) {
    int wid  = threadIdx.x >> 6;
    int lane = threadIdx.x & 63;
    int node = blockIdx.x * (blockDim.x >> 6) + wid;
    if (node >= N_NODES) return;
    int g  = lane >> 4;                              // group 0..3
    int hl = lane & 15;                              // lane in group
    const float4* xn = (const float4*)(x + (size_t)node * D_FEAT);
    float4 a0 = xn[hl * 2];
    float4 a1 = xn[hl * 2 + 1];
    float b0  = beta[0];
    float rnb = rinv[node] * b0;
    float selfw = __expf(b0);                        // self-loop: cos = 1 -> alpha = beta
    float4 acc0, acc1;
    float den;
    if (g == 0) {
        acc0 = make_float4(selfw * a0.x, selfw * a0.y, selfw * a0.z, selfw * a0.w);
        acc1 = make_float4(selfw * a1.x, selfw * a1.y, selfw * a1.z, selfw * a1.w);
        den  = selfw;
    } else {
        acc0 = make_float4(0.f, 0.f, 0.f, 0.f);
        acc1 = make_float4(0.f, 0.f, 0.f, 0.f);
        den  = 0.f;
    }
    int s = offs[node] + bsum[node >> 10];
    int e = (node == N_NODES - 1) ? N_EDGES
                                  : offs[node + 1] + bsum[(node + 1) >> 10];
    for (int p = s; p < e; p += 4) {
        int idx = p + g;
        bool valid = idx < e;
        int c = csr_col[valid ? idx : p];            // tail: clamp to in-range slot (cache hit)
        const float4* xc = (const float4*)(x + (size_t)c * D_FEAT);
        float4 bv0 = xc[hl * 2];
        float4 bv1 = xc[hl * 2 + 1];
        float dot = a0.x * bv0.x + a0.y * bv0.y + a0.z * bv0.z + a0.w * bv0.w
                  + a1.x * bv1.x + a1.y * bv1.y + a1.z * bv1.z + a1.w * bv1.w;
        #pragma unroll
        for (int m = 1; m < 16; m <<= 1) dot += __shfl_xor(dot, m);   // 16-lane reduce
        float w = valid ? __expf(dot * rnb * rinv[c]) : 0.f;
        acc0.x += w * bv0.x; acc0.y += w * bv0.y; acc0.z += w * bv0.z; acc0.w += w * bv0.w;
        acc1.x += w * bv1.x; acc1.y += w * bv1.y; acc1.z += w * bv1.z; acc1.w += w * bv1.w;
        den += w;
    }
    // combine the four groups (same feature mapping in all groups)
    #pragma unroll
    for (int m = 16; m < 64; m <<= 1) {
        acc0.x += __shfl_xor(acc0.x, m); acc0.y += __shfl_xor(acc0.y, m);
        acc0.z += __shfl_xor(acc0.z, m); acc0.w += __shfl_xor(acc0.w, m);
        acc1.x += __shfl_xor(acc1.x, m); acc1.y += __shfl_xor(acc1.y, m);
        acc1.z += __shfl_xor(acc1.z, m); acc1.w += __shfl_xor(acc1.w, m);
        den += __shfl_xor(den, m);
    }
    if (g == 0) {
        float inv = 1.0f / den;
        float4* op = (float4*)(out + (size_t)node * D_FEAT);
        op[hl * 2]     = make_float4(acc0.x * inv, acc0.y * inv, acc0.z * inv, acc0.w * inv);
        op[hl * 2 + 1] = make_float4(acc1.x * inv, acc1.y * inv, acc1.z * inv, acc1.w * inv);
    }
}

extern "C" void kernel_launch(void* const* d_in, const int* in_sizes, int n_in,
                              void* d_out, int out_size, void* d_ws, size_t ws_size,
                              hipStream_t stream) {
    const float* x    = (const float*)d_in[0];
    const float* beta = (const float*)d_in[1];
    const int*   ei   = (const int*)d_in[2];
    const int*   row  = ei;              // edge_index[0] = destination
    const int*   col  = ei + N_EDGES;    // edge_index[1] = source
    float* out = (float*)d_out;

    // workspace layout (4B elements)
    int*   count    = (int*)d_ws;                     // N
    int*   cursor   = count  + N_NODES;               // N
    int*   offs     = cursor + N_NODES;               // N
    int*   blocksum = offs   + N_NODES;               // NB
    float* rinv     = (float*)(blocksum + NB);        // N
    int*   csr_col  = (int*)(rinv + N_NODES);         // E

    zero_kernel<<<(2 * N_NODES + 255) / 256, 256, 0, stream>>>(count, 2 * N_NODES);

    hist_rinv_kernel<<<(N_NODES * 64 + 255) / 256, 256, 0, stream>>>(row, count, x, rinv);

    scan1_kernel<<<NB, SCAN_B, 0, stream>>>(count, offs, blocksum, N_NODES);
    scan2_kernel<<<1, 64, 0, stream>>>(blocksum, NB);

    scatter_kernel<<<(N_EDGES + 255) / 256, 256, 0, stream>>>(row, col, offs, blocksum,
                                                              cursor, csr_col, N_EDGES);

    fused_kernel<<<(N_NODES + 3) / 4, 256, 0, stream>>>(x, beta, rinv, offs, blocksum,
                                                        csr_col, out);
}